// Round 10
// baseline (187.056 us; speedup 1.0000x reference)
//
#include <hip/hip_runtime.h>
#include <hip/hip_bf16.h>
#include <stdint.h>

typedef __attribute__((ext_vector_type(8))) short short8;
typedef __attribute__((ext_vector_type(4))) short short4v;
typedef __attribute__((ext_vector_type(4))) float f32x4;

#define HD 256

__device__ __forceinline__ ushort f2bf(float f) {
  union { float f; uint32_t u; } x; x.f = f;
  uint32_t r = (x.u + 0x7fffu + ((x.u >> 16) & 1u)) >> 16;
  return (ushort)r;
}

// swizzled index (ushort units) into a [rows][256] bf16 LDS buffer.
__device__ __forceinline__ int swz(int row, int col) {
  int chunk = (col >> 3) ^ (row & 7);
  return row * 256 + chunk * 8 + (col & 7);
}

// ---------------- prep: weight bf16 conversion + Wc = Po@Wv fusion -------
__global__ void prep1_kernel(const float* __restrict__ in_proj_w,
                             const float* __restrict__ in_proj_b,
                             const float* __restrict__ out_proj_w,
                             const float* __restrict__ out_proj_b,
                             const float* __restrict__ d1_w,
                             const float* __restrict__ d2_w,
                             const float* __restrict__ W3_w,
                             ushort* __restrict__ Wc_bf, ushort* __restrict__ d1_bf,
                             ushort* __restrict__ d2_bf, ushort* __restrict__ W3_bf,
                             float* __restrict__ bc) {
  int blk = blockIdx.x, t = threadIdx.x;
  if (blk < 256) {
    int i = blk * 256 + t;               // 0..65535
    d1_bf[i] = f2bf(d1_w[i]);
    d2_bf[i] = f2bf(d2_w[i]);
    W3_bf[i] = f2bf(W3_w[i]);
    W3_bf[i + 65536] = f2bf(W3_w[i + 65536]);
  } else {
    int i = blk - 256;                   // Wc row
    const float* Po = out_proj_w + i * HD;
    const float* Wv = in_proj_w + 2 * HD * HD;
    float acc = 0.f;
    for (int m = 0; m < HD; ++m) acc += Po[m] * Wv[m * HD + t];
    Wc_bf[i * HD + t] = f2bf(acc);
    if (t == 0) {
      const float* bv = in_proj_b + 2 * HD;
      float b = out_proj_b[i];
      for (int m = 0; m < HD; ++m) b += Po[m] * bv[m];
      bc[i] = b;
    }
  }
}

// ------- scan: offsets/sections via binary search (batch is sorted) ------
__global__ void scan_kernel(const int* __restrict__ batch, int total_nodes,
                            const int* __restrict__ seq_len,
                            int* __restrict__ sections, int* __restrict__ offsets,
                            int* __restrict__ last_idx, int nsess) {
  __shared__ int lbs[1025];
  __shared__ int s2[1024];
  int t = threadIdx.x;
  if (t < nsess) {
    int lo = 0, hi = total_nodes;        // lower_bound(batch, t)
    while (lo < hi) {
      int mid = (lo + hi) >> 1;
      if (batch[mid] < t) lo = mid + 1; else hi = mid;
    }
    lbs[t] = lo;
  }
  if (t == 0) lbs[nsess] = total_nodes;
  int v2 = (t < nsess) ? seq_len[t] : 0;
  s2[t] = v2;
  for (int d = 1; d < 1024; d <<= 1) {
    __syncthreads();
    int a2 = (t >= d) ? s2[t - d] : 0;
    __syncthreads();
    s2[t] += a2;
  }
  __syncthreads();
  if (t < nsess) {
    offsets[t] = lbs[t];
    sections[t] = lbs[t + 1] - lbs[t];
    last_idx[t] = s2[t] - 1;
  }
}

// ---- one SAN GEMM stage, 16-wave version: each wave owns a 16x16 tile ----
template<bool RELU, bool RESID, bool WACC>
__device__ __forceinline__ void gemm_stage16(const ushort* inA, const ushort* __restrict__ Wbf,
                                             const float* __restrict__ bias,
                                             float* accf, ushort* outB) {
  int t = threadIdx.x;
  int lane = t & 63, wid = t >> 6;       // 16 waves
  int la = lane & 15, g = lane >> 4;
  int col = wid * 16 + la;
  f32x4 acc = {0.f, 0.f, 0.f, 0.f};
#pragma unroll
  for (int kk = 0; kk < 8; ++kk) {
    short8 a = *(const short8*)&inA[swz(la, kk * 32 + g * 8)];
    short8 b = *(const short8*)&Wbf[col * HD + kk * 32 + g * 8];
    acc = __builtin_amdgcn_mfma_f32_16x16x32_bf16(a, b, acc, 0, 0, 0);
  }
  float bia = bias[col];
#pragma unroll
  for (int r = 0; r < 4; ++r) {
    int ro = g * 4 + r;
    float v = acc[r] + bia;
    if (RELU) v = fmaxf(v, 0.f);
    if (RESID) v += accf[ro * HD + col];
    if (WACC) accf[ro * HD + col] = v;
    outB[swz(ro, col)] = f2bf(v);
  }
}

__device__ __forceinline__ void stage_fence() {
  __syncthreads();
  __builtin_amdgcn_sched_barrier(0);
}

// -------- v_n + SAN x3 (3 stages each) + s_h + y_hat (16 rows / block) ---
__global__ __launch_bounds__(1024, 1) void sh_kernel(
    const float* __restrict__ node_emb, const float* __restrict__ emb_w,
    const float* __restrict__ itemset_len,
    const float* __restrict__ d1_b, const float* __restrict__ d2_b,
    const float* __restrict__ W3_b, const float* __restrict__ bc,
    const int* __restrict__ sequence, const int* __restrict__ cue,
    const int* __restrict__ sections, const int* __restrict__ offsets,
    const int* __restrict__ last_idx,
    const ushort* __restrict__ Wc_bf, const ushort* __restrict__ d1_bf,
    const ushort* __restrict__ d2_bf, const ushort* __restrict__ W3_bf,
    ushort* __restrict__ sh_bf, float* __restrict__ y_hat, int group) {
  __shared__ float accf[16 * HD];
  __shared__ ushort vn_bf[16 * HD];
  __shared__ ushort bufA[16 * HD];
  __shared__ ushort bufB[16 * HD];
  int t = threadIdx.x;
  int b0 = blockIdx.x * 16;

  // ---- v_n: gather last-step itemset embedding (1 float4 per thread) ----
  {
    int r = t >> 6, cg = t & 63;
    int sess = b0 + r;
    int li = last_idx[sess];
    float inv = 1.0f / itemset_len[li];
    int sec = sections[sess], off = offsets[sess];
    float4 s = {0.f, 0.f, 0.f, 0.f};
    for (int gi = 0; gi < group; ++gi) {
      int sq = sequence[li * group + gi];
      if (sq == sec) continue;           // padding row -> zero
      float4 v = *(const float4*)(node_emb + (size_t)(off + sq) * HD + cg * 4);
      s.x += v.x; s.y += v.y; s.z += v.z; s.w += v.w;
    }
    short4v u;
    u[0] = (short)f2bf(s.x * inv); u[1] = (short)f2bf(s.y * inv);
    u[2] = (short)f2bf(s.z * inv); u[3] = (short)f2bf(s.w * inv);
    *(short4v*)&vn_bf[swz(r, cg * 4)] = u;
  }
  stage_fence();

  // ---- 3 SAN blocks, 3 stages each (Wc fused) ----
  const ushort* x = vn_bf;
  ushort* P = bufA;
  ushort* Q = bufB;
#pragma unroll 1
  for (int sb = 0; sb < 3; ++sb) {
    gemm_stage16<false, false, true>(x, Wc_bf, bc, accf, P);      // attn (fp32 in accf)
    stage_fence();
    gemm_stage16<true, false, false>(P, d1_bf, d1_b, nullptr, Q); // t2 = relu(attn@d1^T+b1)
    stage_fence();
    gemm_stage16<false, true, false>(Q, d2_bf, d2_b, accf, P);    // x = attn + t2@d2^T+b2
    stage_fence();
    x = P;
    ushort* tmp = P; P = Q; Q = tmp;
  }

  // ---- s_h = [v_n, s_g] @ W3^T + b3 (K=512), 1 col-tile per wave ----
  {
    int lane = t & 63, wid = t >> 6;
    int la = lane & 15, g = lane >> 4;
    int col = wid * 16 + la;
    f32x4 acc = {0.f, 0.f, 0.f, 0.f};
#pragma unroll
    for (int kk = 0; kk < 16; ++kk) {
      const ushort* src = (kk < 8) ? vn_bf : x;
      short8 a = *(const short8*)&src[swz(la, (kk & 7) * 32 + g * 8)];
      short8 b = *(const short8*)&W3_bf[col * 2 * HD + kk * 32 + g * 8];
      acc = __builtin_amdgcn_mfma_f32_16x16x32_bf16(a, b, acc, 0, 0, 0);
    }
    float bia = W3_b[col];
#pragma unroll
    for (int r = 0; r < 4; ++r) {
      int ro = g * 4 + r;
      float v = acc[r] + bia;
      accf[ro * HD + col] = v;
      sh_bf[(size_t)(b0 + ro) * HD + col] = f2bf(v);
    }
  }
  stage_fence();

  // ---- y_hat = dot(s_h, emb[cue]) in fp32; one wave per row ----
  {
    int r = t >> 6, lane = t & 63;
    const float4 er = *(const float4*)(emb_w + (size_t)cue[b0 + r] * HD + lane * 4);
    const float* ar = &accf[r * HD + lane * 4];
    float p = ar[0] * er.x + ar[1] * er.y + ar[2] * er.z + ar[3] * er.w;
#pragma unroll
    for (int off = 32; off >= 1; off >>= 1) p += __shfl_down(p, off, 64);
    if (lane == 0) y_hat[b0 + r] = p;
  }
}

// ---------------- all_scores = s_h @ emb^T  (score v4, unchanged) --------
__global__ __launch_bounds__(256) void score_kernel(
    const ushort* __restrict__ sh_bf, const float* __restrict__ emb_w,
    float* __restrict__ scores, int nrows, int V) {
  __shared__ ushort ebuf[64 * HD];         // 32KB
  __shared__ float obuf[4][16][68];        // wave-private, 17.4KB
  int t = threadIdx.x;
  int c0 = blockIdx.x * 64;
#pragma unroll
  for (int i = 0; i < 8; ++i) {
    int c = t + i * 256;
    int row = c >> 5, q = c & 31;
    if (c0 + row < V) {
      const float4* src = (const float4*)(emb_w + (size_t)(c0 + row) * HD + q * 8);
      float4 v0 = src[0], v1 = src[1];
      short8 u;
      u[0] = (short)f2bf(v0.x); u[1] = (short)f2bf(v0.y);
      u[2] = (short)f2bf(v0.z); u[3] = (short)f2bf(v0.w);
      u[4] = (short)f2bf(v1.x); u[5] = (short)f2bf(v1.y);
      u[6] = (short)f2bf(v1.z); u[7] = (short)f2bf(v1.w);
      *(short8*)&ebuf[row * 256 + ((q ^ (row & 7)) * 8)] = u;
    }
  }
  __syncthreads();

  int lane = t & 63, wid = t >> 6;
  int la = lane & 15, g = lane >> 4;
  int colf = lane & 15;                  // f32x4 column in store phase
  int rquad = lane >> 4;                 // row within quad in store phase
  bool cok = (c0 + colf * 4) < V;
  int nrb = nrows >> 6;
  for (int rb = 0; rb < nrb; ++rb) {
    int r0 = rb * 64 + wid * 16;
    const ushort* arow = sh_bf + (size_t)(r0 + la) * HD;
    short8 a[8];
#pragma unroll
    for (int kk = 0; kk < 8; ++kk) a[kk] = *(const short8*)&arow[kk * 32 + g * 8];
    f32x4 acc[4] = {{0.f,0.f,0.f,0.f},{0.f,0.f,0.f,0.f},{0.f,0.f,0.f,0.f},{0.f,0.f,0.f,0.f}};
#pragma unroll
    for (int kk = 0; kk < 8; ++kk) {
#pragma unroll
      for (int ct = 0; ct < 4; ++ct) {
        int brow = ct * 16 + la;
        short8 b = *(const short8*)&ebuf[brow * 256 + (((kk * 4 + g) ^ (brow & 7)) * 8)];
        acc[ct] = __builtin_amdgcn_mfma_f32_16x16x32_bf16(a[kk], b, acc[ct], 0, 0, 0);
      }
    }
#pragma unroll
    for (int ct = 0; ct < 4; ++ct)
#pragma unroll
      for (int r = 0; r < 4; ++r)
        obuf[wid][g * 4 + r][ct * 16 + la] = acc[ct][r];
#pragma unroll
    for (int i = 0; i < 4; ++i) {
      int row = i * 4 + rquad;
      f32x4 v = *(const f32x4*)&obuf[wid][row][colf * 4];
      if (cok)
        *(f32x4*)&scores[(size_t)(r0 + row) * V + c0 + colf * 4] = v;
    }
  }
}

extern "C" void kernel_launch(void* const* d_in, const int* in_sizes, int n_in,
                              void* d_out, int out_size, void* d_ws, size_t ws_size,
                              hipStream_t stream) {
  const float* node_emb   = (const float*)d_in[0];
  const float* emb_w      = (const float*)d_in[1];
  const float* itemset_len= (const float*)d_in[2];
  const float* in_proj_w  = (const float*)d_in[3];
  const float* in_proj_b  = (const float*)d_in[4];
  const float* out_proj_w = (const float*)d_in[5];
  const float* out_proj_b = (const float*)d_in[6];
  const float* d1_w       = (const float*)d_in[7];
  const float* d1_b       = (const float*)d_in[8];
  const float* d2_w       = (const float*)d_in[9];
  const float* d2_b       = (const float*)d_in[10];
  const float* W3_w       = (const float*)d_in[11];
  const float* W3_b       = (const float*)d_in[12];
  const int*   batch      = (const int*)d_in[13];
  const int*   sequence   = (const int*)d_in[14];
  const int*   seq_len    = (const int*)d_in[15];
  const int*   cue        = (const int*)d_in[16];

  int total_nodes = in_sizes[0] / HD;
  int V           = in_sizes[1] / HD;
  int nsess       = in_sizes[15];
  int total_steps = in_sizes[2];
  int group       = in_sizes[14] / total_steps;

  char* ws = (char*)d_ws;
  int* sections   = (int*)(ws);
  int* offsets    = (int*)(ws + 4096);
  int* last_idx   = (int*)(ws + 8192);
  float* bc       = (float*)(ws + 12288);                  // 256 fp32
  ushort* sh_bf   = (ushort*)(ws + 16384);                 // nsess*256 bf16
  ushort* Wc_bf   = (ushort*)(ws + 16384 + 524288);
  ushort* d1_bf   = Wc_bf + HD * HD;
  ushort* d2_bf   = d1_bf + HD * HD;
  ushort* W3_bf   = d2_bf + HD * HD;

  float* y_hat  = (float*)d_out;
  float* scores = (float*)d_out + nsess;

  // DECOMPOSITION PROBE (round 10): prep, scan, sh each launched TWICE
  // (all idempotent — pure functions of inputs -> ws/out). dur_us delta vs
  // round 9's 141.2 = prep+scan+sh warm execution time. Ledger so far:
  // r6 probe: score_v2=75.5, non-score(old)=78.7. r9: dur=141.2.
  prep1_kernel<<<512, 256, 0, stream>>>(in_proj_w, in_proj_b, out_proj_w, out_proj_b,
                                        d1_w, d2_w, W3_w,
                                        Wc_bf, d1_bf, d2_bf, W3_bf, bc);
  prep1_kernel<<<512, 256, 0, stream>>>(in_proj_w, in_proj_b, out_proj_w, out_proj_b,
                                        d1_w, d2_w, W3_w,
                                        Wc_bf, d1_bf, d2_bf, W3_bf, bc);
  scan_kernel<<<1, 1024, 0, stream>>>(batch, total_nodes, seq_len,
                                      sections, offsets, last_idx, nsess);
  scan_kernel<<<1, 1024, 0, stream>>>(batch, total_nodes, seq_len,
                                      sections, offsets, last_idx, nsess);
  sh_kernel<<<nsess / 16, 1024, 0, stream>>>(node_emb, emb_w, itemset_len,
                                             d1_b, d2_b, W3_b, bc,
                                             sequence, cue, sections, offsets, last_idx,
                                             Wc_bf, d1_bf, d2_bf, W3_bf,
                                             sh_bf, y_hat, group);
  sh_kernel<<<nsess / 16, 1024, 0, stream>>>(node_emb, emb_w, itemset_len,
                                             d1_b, d2_b, W3_b, bc,
                                             sequence, cue, sections, offsets, last_idx,
                                             Wc_bf, d1_bf, d2_bf, W3_bf,
                                             sh_bf, y_hat, group);
  score_kernel<<<(V + 63) / 64, 256, 0, stream>>>(sh_bf, emb_w, scores, nsess, V);
}

// Round 11
// 134.934 us; speedup vs baseline: 1.3863x; 1.3863x over previous
//
#include <hip/hip_runtime.h>
#include <hip/hip_bf16.h>
#include <stdint.h>

typedef __attribute__((ext_vector_type(8))) short short8;
typedef __attribute__((ext_vector_type(4))) short short4v;
typedef __attribute__((ext_vector_type(4))) float f32x4;

#define HD 256

__device__ __forceinline__ ushort f2bf(float f) {
  union { float f; uint32_t u; } x; x.f = f;
  uint32_t r = (x.u + 0x7fffu + ((x.u >> 16) & 1u)) >> 16;
  return (ushort)r;
}

// swizzled index (ushort units) into a [rows][256] bf16 LDS buffer.
__device__ __forceinline__ int swz(int row, int col) {
  int chunk = (col >> 3) ^ (row & 7);
  return row * 256 + chunk * 8 + (col & 7);
}

// ---------------- prep: weight bf16 conversion + Wc = Po@Wv fusion -------
__global__ void prep1_kernel(const float* __restrict__ in_proj_w,
                             const float* __restrict__ in_proj_b,
                             const float* __restrict__ out_proj_w,
                             const float* __restrict__ out_proj_b,
                             const float* __restrict__ d1_w,
                             const float* __restrict__ d2_w,
                             const float* __restrict__ W3_w,
                             ushort* __restrict__ Wc_bf, ushort* __restrict__ d1_bf,
                             ushort* __restrict__ d2_bf, ushort* __restrict__ W3_bf,
                             float* __restrict__ bc) {
  int blk = blockIdx.x, t = threadIdx.x;
  if (blk < 256) {
    int i = blk * 256 + t;               // 0..65535
    d1_bf[i] = f2bf(d1_w[i]);
    d2_bf[i] = f2bf(d2_w[i]);
    W3_bf[i] = f2bf(W3_w[i]);
    W3_bf[i + 65536] = f2bf(W3_w[i + 65536]);
  } else {
    int i = blk - 256;                   // Wc row
    const float* Po = out_proj_w + i * HD;
    const float* Wv = in_proj_w + 2 * HD * HD;
    float acc = 0.f;
    for (int m = 0; m < HD; ++m) acc += Po[m] * Wv[m * HD + t];
    Wc_bf[i * HD + t] = f2bf(acc);
    if (t == 0) {
      const float* bv = in_proj_b + 2 * HD;
      float b = out_proj_b[i];
      for (int m = 0; m < HD; ++m) b += Po[m] * bv[m];
      bc[i] = b;
    }
  }
}

// ------- scan: offsets/sections via binary search (batch is sorted) ------
__global__ void scan_kernel(const int* __restrict__ batch, int total_nodes,
                            const int* __restrict__ seq_len,
                            int* __restrict__ sections, int* __restrict__ offsets,
                            int* __restrict__ last_idx, int nsess) {
  __shared__ int lbs[1025];
  __shared__ int s2[1024];
  int t = threadIdx.x;
  if (t < nsess) {
    int lo = 0, hi = total_nodes;        // lower_bound(batch, t)
    while (lo < hi) {
      int mid = (lo + hi) >> 1;
      if (batch[mid] < t) lo = mid + 1; else hi = mid;
    }
    lbs[t] = lo;
  }
  if (t == 0) lbs[nsess] = total_nodes;
  int v2 = (t < nsess) ? seq_len[t] : 0;
  s2[t] = v2;
  for (int d = 1; d < 1024; d <<= 1) {
    __syncthreads();
    int a2 = (t >= d) ? s2[t - d] : 0;
    __syncthreads();
    s2[t] += a2;
  }
  __syncthreads();
  if (t < nsess) {
    offsets[t] = lbs[t];
    sections[t] = lbs[t + 1] - lbs[t];
    last_idx[t] = s2[t] - 1;
  }
}

// ---- one SAN GEMM stage, 16-wave version: each wave owns a 16x16 tile ----
template<bool RELU, bool RESID, bool WACC>
__device__ __forceinline__ void gemm_stage16(const ushort* inA, const ushort* __restrict__ Wbf,
                                             const float* __restrict__ bias,
                                             float* accf, ushort* outB) {
  int t = threadIdx.x;
  int lane = t & 63, wid = t >> 6;       // 16 waves
  int la = lane & 15, g = lane >> 4;
  int col = wid * 16 + la;
  f32x4 acc = {0.f, 0.f, 0.f, 0.f};
#pragma unroll
  for (int kk = 0; kk < 8; ++kk) {
    short8 a = *(const short8*)&inA[swz(la, kk * 32 + g * 8)];
    short8 b = *(const short8*)&Wbf[col * HD + kk * 32 + g * 8];
    acc = __builtin_amdgcn_mfma_f32_16x16x32_bf16(a, b, acc, 0, 0, 0);
  }
  float bia = bias[col];
#pragma unroll
  for (int r = 0; r < 4; ++r) {
    int ro = g * 4 + r;
    float v = acc[r] + bia;
    if (RELU) v = fmaxf(v, 0.f);
    if (RESID) v += accf[ro * HD + col];
    if (WACC) accf[ro * HD + col] = v;
    outB[swz(ro, col)] = f2bf(v);
  }
}

__device__ __forceinline__ void stage_fence() {
  __syncthreads();
  __builtin_amdgcn_sched_barrier(0);
}

// -------- v_n + SAN x3 (3 stages each) + s_h + y_hat (16 rows / block) ---
__global__ __launch_bounds__(1024, 1) void sh_kernel(
    const float* __restrict__ node_emb, const float* __restrict__ emb_w,
    const float* __restrict__ itemset_len,
    const float* __restrict__ d1_b, const float* __restrict__ d2_b,
    const float* __restrict__ W3_b, const float* __restrict__ bc,
    const int* __restrict__ sequence, const int* __restrict__ cue,
    const int* __restrict__ sections, const int* __restrict__ offsets,
    const int* __restrict__ last_idx,
    const ushort* __restrict__ Wc_bf, const ushort* __restrict__ d1_bf,
    const ushort* __restrict__ d2_bf, const ushort* __restrict__ W3_bf,
    ushort* __restrict__ sh_bf, float* __restrict__ y_hat, int group) {
  __shared__ float accf[16 * HD];
  __shared__ ushort vn_bf[16 * HD];
  __shared__ ushort bufA[16 * HD];
  __shared__ ushort bufB[16 * HD];
  int t = threadIdx.x;
  int b0 = blockIdx.x * 16;

  // ---- v_n: gather last-step itemset embedding (1 float4 per thread) ----
  {
    int r = t >> 6, cg = t & 63;
    int sess = b0 + r;
    int li = last_idx[sess];
    float inv = 1.0f / itemset_len[li];
    int sec = sections[sess], off = offsets[sess];
    float4 s = {0.f, 0.f, 0.f, 0.f};
    for (int gi = 0; gi < group; ++gi) {
      int sq = sequence[li * group + gi];
      if (sq == sec) continue;           // padding row -> zero
      float4 v = *(const float4*)(node_emb + (size_t)(off + sq) * HD + cg * 4);
      s.x += v.x; s.y += v.y; s.z += v.z; s.w += v.w;
    }
    short4v u;
    u[0] = (short)f2bf(s.x * inv); u[1] = (short)f2bf(s.y * inv);
    u[2] = (short)f2bf(s.z * inv); u[3] = (short)f2bf(s.w * inv);
    *(short4v*)&vn_bf[swz(r, cg * 4)] = u;
  }
  stage_fence();

  // ---- 3 SAN blocks, 3 stages each (Wc fused) ----
  const ushort* x = vn_bf;
  ushort* P = bufA;
  ushort* Q = bufB;
#pragma unroll 1
  for (int sb = 0; sb < 3; ++sb) {
    gemm_stage16<false, false, true>(x, Wc_bf, bc, accf, P);      // attn (fp32 in accf)
    stage_fence();
    gemm_stage16<true, false, false>(P, d1_bf, d1_b, nullptr, Q); // t2 = relu(attn@d1^T+b1)
    stage_fence();
    gemm_stage16<false, true, false>(Q, d2_bf, d2_b, accf, P);    // x = attn + t2@d2^T+b2
    stage_fence();
    x = P;
    ushort* tmp = P; P = Q; Q = tmp;
  }

  // ---- s_h = [v_n, s_g] @ W3^T + b3 (K=512), 1 col-tile per wave ----
  {
    int lane = t & 63, wid = t >> 6;
    int la = lane & 15, g = lane >> 4;
    int col = wid * 16 + la;
    f32x4 acc = {0.f, 0.f, 0.f, 0.f};
#pragma unroll
    for (int kk = 0; kk < 16; ++kk) {
      const ushort* src = (kk < 8) ? vn_bf : x;
      short8 a = *(const short8*)&src[swz(la, (kk & 7) * 32 + g * 8)];
      short8 b = *(const short8*)&W3_bf[col * 2 * HD + kk * 32 + g * 8];
      acc = __builtin_amdgcn_mfma_f32_16x16x32_bf16(a, b, acc, 0, 0, 0);
    }
    float bia = W3_b[col];
#pragma unroll
    for (int r = 0; r < 4; ++r) {
      int ro = g * 4 + r;
      float v = acc[r] + bia;
      accf[ro * HD + col] = v;
      sh_bf[(size_t)(b0 + ro) * HD + col] = f2bf(v);
    }
  }
  stage_fence();

  // ---- y_hat = dot(s_h, emb[cue]) in fp32; one wave per row ----
  {
    int r = t >> 6, lane = t & 63;
    const float4 er = *(const float4*)(emb_w + (size_t)cue[b0 + r] * HD + lane * 4);
    const float* ar = &accf[r * HD + lane * 4];
    float p = ar[0] * er.x + ar[1] * er.y + ar[2] * er.z + ar[3] * er.w;
#pragma unroll
    for (int off = 32; off >= 1; off >>= 1) p += __shfl_down(p, off, 64);
    if (lane == 0) y_hat[b0 + r] = p;
  }
}

// ---------------- all_scores = s_h @ emb^T  (score v5 = v2 + NT) ---------
// EXACT v2 structure (64-col tile, obuf[64][65], one-row-per-instruction
// wave-wide dword stores, 256B runs — measured 75.5us in the r6 probe;
// multi-row-per-instruction variants v3/v4 both regressed to ~90us).
// Single change: nontemporal on the scalar store — streaming 205MB should
// bypass L2 so it keeps serving ebuf/sh reads.
__global__ __launch_bounds__(256) void score_kernel(
    const ushort* __restrict__ sh_bf, const float* __restrict__ emb_w,
    float* __restrict__ scores, int nrows, int V) {
  __shared__ ushort ebuf[64 * HD];
  __shared__ float obuf[64][65];
  int t = threadIdx.x;
  int c0 = blockIdx.x * 64;
#pragma unroll
  for (int i = 0; i < 8; ++i) {
    int c = t + i * 256;
    int row = c >> 5, q = c & 31;
    if (c0 + row < V) {
      const float4* src = (const float4*)(emb_w + (size_t)(c0 + row) * HD + q * 8);
      float4 v0 = src[0], v1 = src[1];
      short8 u;
      u[0] = (short)f2bf(v0.x); u[1] = (short)f2bf(v0.y);
      u[2] = (short)f2bf(v0.z); u[3] = (short)f2bf(v0.w);
      u[4] = (short)f2bf(v1.x); u[5] = (short)f2bf(v1.y);
      u[6] = (short)f2bf(v1.z); u[7] = (short)f2bf(v1.w);
      *(short8*)&ebuf[row * 256 + ((q ^ (row & 7)) * 8)] = u;
    }
  }
  __syncthreads();

  int lane = t & 63, wid = t >> 6;
  int la = lane & 15, g = lane >> 4;
  int nrb = nrows >> 6;
  int cg = c0 + lane;
  bool cok = cg < V;
  for (int rb = 0; rb < nrb; ++rb) {
    int r0 = rb * 64 + wid * 16;
    const ushort* arow = sh_bf + (size_t)(r0 + la) * HD;
    short8 a[8];
#pragma unroll
    for (int kk = 0; kk < 8; ++kk) a[kk] = *(const short8*)&arow[kk * 32 + g * 8];
    f32x4 acc[4] = {{0.f,0.f,0.f,0.f},{0.f,0.f,0.f,0.f},{0.f,0.f,0.f,0.f},{0.f,0.f,0.f,0.f}};
#pragma unroll
    for (int kk = 0; kk < 8; ++kk) {
#pragma unroll
      for (int ct = 0; ct < 4; ++ct) {
        int brow = ct * 16 + la;
        short8 b = *(const short8*)&ebuf[brow * 256 + (((kk * 4 + g) ^ (brow & 7)) * 8)];
        acc[ct] = __builtin_amdgcn_mfma_f32_16x16x32_bf16(a[kk], b, acc[ct], 0, 0, 0);
      }
    }
    // stage result tile in LDS (rows wid*16..wid*16+15 are wave-private)
#pragma unroll
    for (int ct = 0; ct < 4; ++ct)
#pragma unroll
      for (int r = 0; r < 4; ++r)
        obuf[wid * 16 + g * 4 + r][ct * 16 + la] = acc[ct][r];
    // wave-wide 256B contiguous NT stores, one output row at a time
#pragma unroll
    for (int i = 0; i < 16; ++i) {
      int row = wid * 16 + i;
      float v = obuf[row][lane];
      if (cok)
        __builtin_nontemporal_store(v, &scores[(size_t)(rb * 64 + row) * V + cg]);
    }
  }
}

extern "C" void kernel_launch(void* const* d_in, const int* in_sizes, int n_in,
                              void* d_out, int out_size, void* d_ws, size_t ws_size,
                              hipStream_t stream) {
  const float* node_emb   = (const float*)d_in[0];
  const float* emb_w      = (const float*)d_in[1];
  const float* itemset_len= (const float*)d_in[2];
  const float* in_proj_w  = (const float*)d_in[3];
  const float* in_proj_b  = (const float*)d_in[4];
  const float* out_proj_w = (const float*)d_in[5];
  const float* out_proj_b = (const float*)d_in[6];
  const float* d1_w       = (const float*)d_in[7];
  const float* d1_b       = (const float*)d_in[8];
  const float* d2_w       = (const float*)d_in[9];
  const float* d2_b       = (const float*)d_in[10];
  const float* W3_w       = (const float*)d_in[11];
  const float* W3_b       = (const float*)d_in[12];
  const int*   batch      = (const int*)d_in[13];
  const int*   sequence   = (const int*)d_in[14];
  const int*   seq_len    = (const int*)d_in[15];
  const int*   cue        = (const int*)d_in[16];

  int total_nodes = in_sizes[0] / HD;
  int V           = in_sizes[1] / HD;
  int nsess       = in_sizes[15];
  int total_steps = in_sizes[2];
  int group       = in_sizes[14] / total_steps;

  char* ws = (char*)d_ws;
  int* sections   = (int*)(ws);
  int* offsets    = (int*)(ws + 4096);
  int* last_idx   = (int*)(ws + 8192);
  float* bc       = (float*)(ws + 12288);                  // 256 fp32
  ushort* sh_bf   = (ushort*)(ws + 16384);                 // nsess*256 bf16
  ushort* Wc_bf   = (ushort*)(ws + 16384 + 524288);
  ushort* d1_bf   = Wc_bf + HD * HD;
  ushort* d2_bf   = d1_bf + HD * HD;
  ushort* W3_bf   = d2_bf + HD * HD;

  float* y_hat  = (float*)d_out;
  float* scores = (float*)d_out + nsess;

  // Ledger: non-score warm = 45.9us (r10 probe); score_v2 = 75.5us (r6
  // probe); v3 ~92.7, v4 ~90-95 (multi-row stores regress). This round:
  // v2-exact + NT stores.
  prep1_kernel<<<512, 256, 0, stream>>>(in_proj_w, in_proj_b, out_proj_w, out_proj_b,
                                        d1_w, d2_w, W3_w,
                                        Wc_bf, d1_bf, d2_bf, W3_bf, bc);
  scan_kernel<<<1, 1024, 0, stream>>>(batch, total_nodes, seq_len,
                                      sections, offsets, last_idx, nsess);
  sh_kernel<<<nsess / 16, 1024, 0, stream>>>(node_emb, emb_w, itemset_len,
                                             d1_b, d2_b, W3_b, bc,
                                             sequence, cue, sections, offsets, last_idx,
                                             Wc_bf, d1_bf, d2_bf, W3_bf,
                                             sh_bf, y_hat, group);
  score_kernel<<<(V + 63) / 64, 256, 0, stream>>>(sh_bf, emb_w, scores, nsess, V);
}